// Round 2
// baseline (429.110 us; speedup 1.0000x reference)
//
#include <hip/hip_runtime.h>
#include <hip/hip_bf16.h>

// SoftmaxRBM: prob = softmax_groups16( hidden @ W^T + a ), all fp32 I/O.
// GEMM via bf16 MFMA (fp32->bf16 truncation in staging; 2%-of-max threshold
// leaves ~20x headroom). A = W [NVIS][NH] (M=v), B = hidden [POP][NH] (N=b).
// C[m=v][n=b]; softmax along m within 16-row groups = one 16x16 MFMA tile,
// so the 16-way reduction is 2 in-lane steps + shfl_xor(16,32).

typedef short  bf16x8 __attribute__((ext_vector_type(8)));
typedef float  f32x4  __attribute__((ext_vector_type(4)));

#define NH    256     // K (N_HIDDEN)
#define POP   1024    // N (batch)
#define NVIS  65536   // M (visible)
#define BM    128
#define BN    128
#define BK    32

__device__ __forceinline__ unsigned pack2bf(float lo, float hi) {
  // two fp32 -> packed bf16x2 (truncate; RNE unnecessary at 2e-3 threshold)
  return (__float_as_uint(hi) & 0xffff0000u) | (__float_as_uint(lo) >> 16);
}

__global__ __launch_bounds__(256) void rbm_softmax_kernel(
    const float* __restrict__ Wg,   // [NVIS][NH]
    const float* __restrict__ Hg,   // [POP][NH]
    const float* __restrict__ Ag,   // [NVIS]
    float* __restrict__ out)        // [POP][NVIS]
{
  __shared__ short sA[BM * BK];  // 8 KB bf16 [128][32], K-contig
  __shared__ short sB[BN * BK];  // 8 KB

  const int tid  = threadIdx.x;
  const int lane = tid & 63;
  const int wave = tid >> 6;
  const int wm   = wave & 1;     // 2x2 wave grid, each wave 64(m) x 64(n)
  const int wn   = wave >> 1;
  const int quad = lane >> 4;
  const int col  = lane & 15;

  const int m_base = blockIdx.y * BM;   // visible block
  const int n_base = blockIdx.x * BN;   // batch block (fastest -> W L2 reuse)

  // staging decomposition: 1024 float4-chunks per tile, 4 per thread
  const int r0  = tid >> 3;      // 0..31  (row within group of 32)
  const int c0  = (tid & 7) * 4; // float col within row: 0,4,...,28

  f32x4 acc[4][4];
  #pragma unroll
  for (int i = 0; i < 4; ++i)
    #pragma unroll
    for (int j = 0; j < 4; ++j)
      acc[i][j] = f32x4{0.f, 0.f, 0.f, 0.f};

  for (int kk = 0; kk < NH / BK; ++kk) {
    const int k0 = kk * BK;
    if (kk) __syncthreads();     // all waves done reading LDS of prev iter

    const float* pa = Wg + (size_t)(m_base + r0) * NH + k0 + c0;
    const float* pb = Hg + (size_t)(n_base + r0) * NH + k0 + c0;
    #pragma unroll
    for (int i = 0; i < 4; ++i) {          // rows r0, r0+32, r0+64, r0+96
      const float4 fa = *(const float4*)(pa + (size_t)i * 32 * NH);
      const float4 fb = *(const float4*)(pb + (size_t)i * 32 * NH);
      uint2 ua, ub;
      ua.x = pack2bf(fa.x, fa.y); ua.y = pack2bf(fa.z, fa.w);
      ub.x = pack2bf(fb.x, fb.y); ub.y = pack2bf(fb.z, fb.w);
      *(uint2*)&sA[(i * 32 + r0) * BK + c0] = ua;   // 8B aligned
      *(uint2*)&sB[(i * 32 + r0) * BK + c0] = ub;
    }
    __syncthreads();

    bf16x8 af[4], bfr[4];
    #pragma unroll
    for (int mt = 0; mt < 4; ++mt)
      af[mt] = *(const bf16x8*)&sA[(wm * 64 + mt * 16 + col) * BK + quad * 8];
    #pragma unroll
    for (int nt = 0; nt < 4; ++nt)
      bfr[nt] = *(const bf16x8*)&sB[(wn * 64 + nt * 16 + col) * BK + quad * 8];

    #pragma unroll
    for (int mt = 0; mt < 4; ++mt)
      #pragma unroll
      for (int nt = 0; nt < 4; ++nt)
        acc[mt][nt] = __builtin_amdgcn_mfma_f32_16x16x32_bf16(
            af[mt], bfr[nt], acc[mt][nt], 0, 0, 0);
  }

  // Epilogue: + a[v], softmax over 16 v-rows per tile, fp32 store.
  // C/D layout: col(n)=lane&15, row(m)=quad*4+reg -> lane holds 4 consecutive v.
  #pragma unroll
  for (int mt = 0; mt < 4; ++mt) {
    const int v0 = m_base + wm * 64 + mt * 16 + quad * 4;
    const float4 av = *(const float4*)(Ag + v0);
    #pragma unroll
    for (int nt = 0; nt < 4; ++nt) {
      const int b = n_base + wn * 64 + nt * 16 + col;
      f32x4 c = acc[mt][nt];
      float x0 = c[0] + av.x, x1 = c[1] + av.y;
      float x2 = c[2] + av.z, x3 = c[3] + av.w;
      float mx = fmaxf(fmaxf(x0, x1), fmaxf(x2, x3));
      mx = fmaxf(mx, __shfl_xor(mx, 16));   // combine 4 quads = 16 rows
      mx = fmaxf(mx, __shfl_xor(mx, 32));
      float e0 = __expf(x0 - mx), e1 = __expf(x1 - mx);
      float e2 = __expf(x2 - mx), e3 = __expf(x3 - mx);
      float s = (e0 + e1) + (e2 + e3);
      s += __shfl_xor(s, 16);
      s += __shfl_xor(s, 32);
      const float inv = 1.0f / s;
      float4 o;
      o.x = e0 * inv; o.y = e1 * inv; o.z = e2 * inv; o.w = e3 * inv;
      *(float4*)(out + (size_t)b * NVIS + v0) = o;   // 16B aligned
    }
  }
}

extern "C" void kernel_launch(void* const* d_in, const int* in_sizes, int n_in,
                              void* d_out, int out_size, void* d_ws, size_t ws_size,
                              hipStream_t stream) {
  const float* hidden = (const float*)d_in[0]; // [1024][256]
  const float* W      = (const float*)d_in[1]; // [65536][256]
  const float* a      = (const float*)d_in[2]; // [65536]
  float* out          = (float*)d_out;         // [1024][65536]

  dim3 grid(POP / BN, NVIS / BM);   // (8, 512), x fastest for W-tile L2 reuse
  rbm_softmax_kernel<<<grid, 256, 0, stream>>>(W, hidden, a, out);
}

// Round 4
// 394.471 us; speedup vs baseline: 1.0878x; 1.0878x over previous
//
#include <hip/hip_runtime.h>
#include <hip/hip_bf16.h>

// SoftmaxRBM: prob = softmax_groups16( hidden @ W^T + a ), fp32 I/O.
// Phase 1: convert W,H fp32->bf16 into d_ws.
// Phase 2: m97-recipe bf16 MFMA GEMM (global_load_lds 16B staging) + fused
//          segmented softmax epilogue, non-temporal fp32 stores.
// A = W [NVIS][NH] (M=v), B = hidden [POP][NH] (N=b); C[m=v][n=b]; softmax
// along m within 16-row groups = one 16x16 MFMA tile (row=quad*4+reg).

typedef short  bf16x8 __attribute__((ext_vector_type(8)));
typedef float  f32x4  __attribute__((ext_vector_type(4)));

#define NH    256
#define POP   1024
#define NVIS  65536
#define BM    128
#define BN    128
#define BK    32

__device__ __forceinline__ void gld16(void* lds, const void* g) {
  __builtin_amdgcn_global_load_lds(
      (const __attribute__((address_space(1))) void*)g,
      (__attribute__((address_space(3))) void*)lds,
      16, 0, 0);
}
__device__ __forceinline__ unsigned pack2bf(float lo, float hi) {
  return (__float_as_uint(hi) & 0xffff0000u) | (__float_as_uint(lo) >> 16);
}

// ---------------- Phase 1: fp32 -> bf16 convert (grid-stride, 8 elem/iter)
__global__ __launch_bounds__(256) void cvt_bf16_kernel(
    const float* __restrict__ src, unsigned short* __restrict__ dst, int n8) {
  int i = blockIdx.x * blockDim.x + threadIdx.x;
  const int stride = gridDim.x * blockDim.x;
  for (; i < n8; i += stride) {
    const float4 f0 = ((const float4*)src)[2 * i];
    const float4 f1 = ((const float4*)src)[2 * i + 1];
    uint4 o;
    o.x = pack2bf(f0.x, f0.y); o.y = pack2bf(f0.z, f0.w);
    o.z = pack2bf(f1.x, f1.y); o.w = pack2bf(f1.z, f1.w);
    ((uint4*)dst)[i] = o;
  }
}

// ---------------- Phase 2: MFMA GEMM + segmented softmax (m97 recipe)
__global__ __launch_bounds__(256) void rbm_gemm_kernel(
    const unsigned short* __restrict__ Wb,   // [NVIS][NH] bf16 (ws)
    const unsigned short* __restrict__ Hb,   // [POP][NH]  bf16 (ws)
    const float* __restrict__ Ag,            // [NVIS] fp32 bias
    float* __restrict__ out)                 // [POP][NVIS] fp32
{
  __shared__ short sA[BM * BK];  // 8 KB [128][32] K-contig, unpadded (gld-lds)
  __shared__ short sB[BN * BK];  // 8 KB

  const int tid  = threadIdx.x;
  const int lane = tid & 63;
  const int wave = tid >> 6;
  const int wm   = wave & 1;
  const int wn   = wave >> 1;
  const int quad = lane >> 4;
  const int col  = lane & 15;

  const int m_base = blockIdx.y * BM;
  const int n_base = blockIdx.x * BN;

  f32x4 acc[4][4];
  #pragma unroll
  for (int i = 0; i < 4; ++i)
    #pragma unroll
    for (int j = 0; j < 4; ++j)
      acc[i][j] = f32x4{0.f, 0.f, 0.f, 0.f};

  for (int kk = 0; kk < NH / BK; ++kk) {
    const int k0 = kk * BK;
    if (kk) __syncthreads();

    // 512 x 16B chunks per tile, 2 per thread per tile.
    // LDS dest = wave-uniform base + lane*16 (required by global_load_lds).
    #pragma unroll
    for (int t = 0; t < 2; ++t) {
      const int c   = t * 256 + tid;   // 0..511
      const int row = c >> 2;          // 0..127
      const int cio = (c & 3) * 8;     // bf16 elem offset: 0,8,16,24
      gld16(&sA[row * BK + cio], Wb + (size_t)(m_base + row) * NH + k0 + cio);
      gld16(&sB[row * BK + cio], Hb + (size_t)(n_base + row) * NH + k0 + cio);
    }
    __syncthreads();   // drains vmcnt (global_load_lds) + barrier

    bf16x8 af[4], bfr[4];
    #pragma unroll
    for (int mt = 0; mt < 4; ++mt)
      af[mt] = *(const bf16x8*)&sA[(wm * 64 + mt * 16 + col) * BK + quad * 8];
    #pragma unroll
    for (int nt = 0; nt < 4; ++nt)
      bfr[nt] = *(const bf16x8*)&sB[(wn * 64 + nt * 16 + col) * BK + quad * 8];

    #pragma unroll
    for (int mt = 0; mt < 4; ++mt)
      #pragma unroll
      for (int nt = 0; nt < 4; ++nt)
        acc[mt][nt] = __builtin_amdgcn_mfma_f32_16x16x32_bf16(
            af[mt], bfr[nt], acc[mt][nt], 0, 0, 0);
  }

  // Epilogue: + a[v], softmax over 16 v-rows (rows of one MFMA tile), store.
  // C/D: col(n)=lane&15, row(m)=quad*4+reg -> lane holds 4 consecutive v.
  #pragma unroll
  for (int mt = 0; mt < 4; ++mt) {
    const int v0 = m_base + wm * 64 + mt * 16 + quad * 4;
    const float4 av = *(const float4*)(Ag + v0);
    #pragma unroll
    for (int nt = 0; nt < 4; ++nt) {
      const int b = n_base + wn * 64 + nt * 16 + col;
      f32x4 c = acc[mt][nt];
      float x0 = c[0] + av.x, x1 = c[1] + av.y;
      float x2 = c[2] + av.z, x3 = c[3] + av.w;
      float mx = fmaxf(fmaxf(x0, x1), fmaxf(x2, x3));
      mx = fmaxf(mx, __shfl_xor(mx, 16));
      mx = fmaxf(mx, __shfl_xor(mx, 32));
      float e0 = __expf(x0 - mx), e1 = __expf(x1 - mx);
      float e2 = __expf(x2 - mx), e3 = __expf(x3 - mx);
      float s = (e0 + e1) + (e2 + e3);
      s += __shfl_xor(s, 16);
      s += __shfl_xor(s, 32);
      const float inv = 1.0f / s;
      f32x4 o;
      o[0] = e0 * inv; o[1] = e1 * inv; o[2] = e2 * inv; o[3] = e3 * inv;
      // non-temporal: don't let 268 MB of streaming writes evict W from L2/L3.
      // NOTE: must use ext_vector_type ptr — HIP float4* rejected by builtin.
      __builtin_nontemporal_store(o, (f32x4*)(out + (size_t)b * NVIS + v0));
    }
  }
}

// ---------------- Fallback (round-1 kernel): fp32 staging, used if ws too small
__global__ __launch_bounds__(256) void rbm_softmax_fb(
    const float* __restrict__ Wg, const float* __restrict__ Hg,
    const float* __restrict__ Ag, float* __restrict__ out)
{
  __shared__ short sA[BM * BK];
  __shared__ short sB[BN * BK];
  const int tid = threadIdx.x, lane = tid & 63, wave = tid >> 6;
  const int wm = wave & 1, wn = wave >> 1, quad = lane >> 4, col = lane & 15;
  const int m_base = blockIdx.y * BM, n_base = blockIdx.x * BN;
  const int r0 = tid >> 3, c0 = (tid & 7) * 4;
  f32x4 acc[4][4];
  #pragma unroll
  for (int i = 0; i < 4; ++i)
    #pragma unroll
    for (int j = 0; j < 4; ++j) acc[i][j] = f32x4{0.f, 0.f, 0.f, 0.f};
  for (int kk = 0; kk < NH / BK; ++kk) {
    const int k0 = kk * BK;
    if (kk) __syncthreads();
    const float* pa = Wg + (size_t)(m_base + r0) * NH + k0 + c0;
    const float* pb = Hg + (size_t)(n_base + r0) * NH + k0 + c0;
    #pragma unroll
    for (int i = 0; i < 4; ++i) {
      const float4 fa = *(const float4*)(pa + (size_t)i * 32 * NH);
      const float4 fb = *(const float4*)(pb + (size_t)i * 32 * NH);
      uint2 ua, ub;
      ua.x = pack2bf(fa.x, fa.y); ua.y = pack2bf(fa.z, fa.w);
      ub.x = pack2bf(fb.x, fb.y); ub.y = pack2bf(fb.z, fb.w);
      *(uint2*)&sA[(i * 32 + r0) * BK + c0] = ua;
      *(uint2*)&sB[(i * 32 + r0) * BK + c0] = ub;
    }
    __syncthreads();
    bf16x8 af[4], bfr[4];
    #pragma unroll
    for (int mt = 0; mt < 4; ++mt)
      af[mt] = *(const bf16x8*)&sA[(wm * 64 + mt * 16 + col) * BK + quad * 8];
    #pragma unroll
    for (int nt = 0; nt < 4; ++nt)
      bfr[nt] = *(const bf16x8*)&sB[(wn * 64 + nt * 16 + col) * BK + quad * 8];
    #pragma unroll
    for (int mt = 0; mt < 4; ++mt)
      #pragma unroll
      for (int nt = 0; nt < 4; ++nt)
        acc[mt][nt] = __builtin_amdgcn_mfma_f32_16x16x32_bf16(
            af[mt], bfr[nt], acc[mt][nt], 0, 0, 0);
  }
  #pragma unroll
  for (int mt = 0; mt < 4; ++mt) {
    const int v0 = m_base + wm * 64 + mt * 16 + quad * 4;
    const float4 av = *(const float4*)(Ag + v0);
    #pragma unroll
    for (int nt = 0; nt < 4; ++nt) {
      const int b = n_base + wn * 64 + nt * 16 + col;
      f32x4 c = acc[mt][nt];
      float x0 = c[0] + av.x, x1 = c[1] + av.y;
      float x2 = c[2] + av.z, x3 = c[3] + av.w;
      float mx = fmaxf(fmaxf(x0, x1), fmaxf(x2, x3));
      mx = fmaxf(mx, __shfl_xor(mx, 16));
      mx = fmaxf(mx, __shfl_xor(mx, 32));
      float e0 = __expf(x0 - mx), e1 = __expf(x1 - mx);
      float e2 = __expf(x2 - mx), e3 = __expf(x3 - mx);
      float s = (e0 + e1) + (e2 + e3);
      s += __shfl_xor(s, 16); s += __shfl_xor(s, 32);
      const float inv = 1.0f / s;
      float4 o;
      o.x = e0 * inv; o.y = e1 * inv; o.z = e2 * inv; o.w = e3 * inv;
      *(float4*)(out + (size_t)b * NVIS + v0) = o;
    }
  }
}

extern "C" void kernel_launch(void* const* d_in, const int* in_sizes, int n_in,
                              void* d_out, int out_size, void* d_ws, size_t ws_size,
                              hipStream_t stream) {
  const float* hidden = (const float*)d_in[0]; // [1024][256]
  const float* W      = (const float*)d_in[1]; // [65536][256]
  const float* a      = (const float*)d_in[2]; // [65536]
  float* out          = (float*)d_out;         // [1024][65536]

  const size_t w_elems = (size_t)NVIS * NH;    // 16,777,216
  const size_t h_elems = (size_t)POP * NH;     // 262,144
  const size_t need = (w_elems + h_elems) * sizeof(unsigned short);

  dim3 grid(POP / BN, NVIS / BM);              // (8, 512)

  if (ws_size >= need) {
    unsigned short* Wb = (unsigned short*)d_ws;
    unsigned short* Hb = Wb + w_elems;
    cvt_bf16_kernel<<<2048, 256, 0, stream>>>(W, Wb, (int)(w_elems / 8));
    cvt_bf16_kernel<<<128, 256, 0, stream>>>(hidden, Hb, (int)(h_elems / 8));
    rbm_gemm_kernel<<<grid, 256, 0, stream>>>(Wb, Hb, a, out);
  } else {
    rbm_softmax_fb<<<grid, 256, 0, stream>>>(W, hidden, a, out);
  }
}